// Round 3
// baseline (9490.009 us; speedup 1.0000x reference)
//
#include <hip/hip_runtime.h>

#define HID 1024
#define OUTD 768

typedef __attribute__((ext_vector_type(8))) __bf16 bf16x8;
typedef __attribute__((ext_vector_type(8))) short s16x8;
typedef __attribute__((ext_vector_type(4))) float f32x4;

__device__ __forceinline__ short f2bf(float f) {
  unsigned u = __builtin_bit_cast(unsigned, f);
  u = (u + 0x7fffu + ((u >> 16) & 1u)) >> 16;   // RNE
  return (short)u;
}

__device__ __forceinline__ s16x8 cvt8(float4 a, float4 b) {
  s16x8 r;
  r[0] = f2bf(a.x); r[1] = f2bf(a.y); r[2] = f2bf(a.z); r[3] = f2bf(a.w);
  r[4] = f2bf(b.x); r[5] = f2bf(b.y); r[6] = f2bf(b.z); r[7] = f2bf(b.w);
  return r;
}

__device__ __forceinline__ f32x4 mfma16(bf16x8 a, bf16x8 b, f32x4 c) {
  return __builtin_amdgcn_mfma_f32_16x16x32_bf16(a, b, c, 0, 0, 0);
}

// ---- pack kernels -------------------------------------------------------

// W_hh [3072][1024] -> Wcomb packed [t=128][kc=128][c=48][8], slabs c in [24,48)
__global__ void k_pack_whh(const float* __restrict__ whh, short* __restrict__ wcomb) {
  int id = blockIdx.x * 256 + threadIdx.x;        // 3072*128
  int i = id >> 7, kc = id & 127;
  const float* s = whh + i * HID + kc * 8;
  int g = i >> 10, j = i & 1023;
  int dst = (((j >> 3) * 128 + kc) * 48 + 24 + g * 8 + (j & 7)) * 8;
  *(s16x8*)(wcomb + dst) = cvt8(*(const float4*)s, *(const float4*)(s + 4));
}

// W_fc [768][1024] -> FC-B packed [kc=128][n=768][8]  (k-dim = HID)
__global__ void k_pack_wfc(const float* __restrict__ wfc, short* __restrict__ wfcp) {
  int id = blockIdx.x * 256 + threadIdx.x;        // 768*128
  int r = id >> 7, c8 = id & 127;
  const float* s = wfc + r * HID + c8 * 8;
  *(s16x8*)(wfcp + (c8 * OUTD + r) * 8) = cvt8(*(const float4*)s, *(const float4*)(s + 4));
}

// W_fc [768][1024] -> Wc-B packed [kc=96][n=1024][8]  (k-dim = OUTD)
__global__ void k_pack_wfc2(const float* __restrict__ wfc, short* __restrict__ wfc2p) {
  int id = blockIdx.x * 256 + threadIdx.x;        // 96*1024
  int r8 = id >> 10, c = id & 1023;
  s16x8 v;
#pragma unroll
  for (int p = 0; p < 8; ++p) v[p] = f2bf(wfc[(r8 * 8 + p) * HID + c]);
  *(s16x8*)(wfc2p + (r8 * HID + c) * 8) = v;
}

__global__ void k_h0(const float* __restrict__ hidden, short* __restrict__ h0,
                     unsigned* __restrict__ cnt) {
  int id = blockIdx.x * 256 + threadIdx.x;        // 262144
  h0[id] = f2bf(hidden[id]);
  if (id == 0) *cnt = 0u;
}

// bc[i] = b_ih[i] + sum_o W_ih[i][o] * b_fc[o]
__global__ void k_bc(const float* __restrict__ wih, const float* __restrict__ bih,
                     const float* __restrict__ bfc, float* __restrict__ bc) {
  int w = threadIdx.x >> 6, lane = threadIdx.x & 63;
  int i = blockIdx.x * 4 + w;                     // grid 768
  float s = 0.f;
#pragma unroll
  for (int it = 0; it < 12; ++it) {
    int o = lane + it * 64;
    s += wih[i * OUTD + o] * bfc[o];
  }
  for (int off = 32; off; off >>= 1) s += __shfl_down(s, off);
  if (lane == 0) bc[i] = bih[i] + s;
}

__global__ void k_flag(float* out, int n) {
  int i = blockIdx.x * 256 + threadIdx.x;
  if (i < n) out[i] = 12345.0f;
}

// ---- GEMM: gi0 = src0 @ W_ih.T + b_ih   (A f32 [256][768], Bt f32 [3072][768])
__global__ __launch_bounds__(256) void k_gemm_bt(
    const float* __restrict__ A, const float* __restrict__ Bt,
    const float* __restrict__ bias, float* __restrict__ out) {
  __shared__ short As[128 * 72];
  __shared__ short Bs[128 * 72];
  const int n0 = blockIdx.x * 128, m0 = blockIdx.y * 128;
  const int tid = threadIdx.x;
  const int w = tid >> 6, ln = tid & 15, q = (tid >> 4) & 3;
  f32x4 acc[2][8] = {};
  for (int kb = 0; kb < 768; kb += 64) {
#pragma unroll
    for (int rep = 0; rep < 4; ++rep) {
      int id = tid + rep * 256;
      int row = id >> 3, cc = id & 7;
      const float* sa = A + (m0 + row) * OUTD + kb + cc * 8;
      *(s16x8*)&As[row * 72 + cc * 8] = cvt8(*(const float4*)sa, *(const float4*)(sa + 4));
      const float* sb = Bt + (n0 + row) * OUTD + kb + cc * 8;
      *(s16x8*)&Bs[row * 72 + cc * 8] = cvt8(*(const float4*)sb, *(const float4*)(sb + 4));
    }
    __syncthreads();
#pragma unroll
    for (int ks = 0; ks < 2; ++ks) {
      bf16x8 a0 = *(const bf16x8*)&As[(w * 32 + ln) * 72 + ks * 32 + q * 8];
      bf16x8 a1 = *(const bf16x8*)&As[(w * 32 + 16 + ln) * 72 + ks * 32 + q * 8];
#pragma unroll
      for (int nf = 0; nf < 8; ++nf) {
        bf16x8 b = *(const bf16x8*)&Bs[(nf * 16 + ln) * 72 + ks * 32 + q * 8];
        acc[0][nf] = mfma16(a0, b, acc[0][nf]);
        acc[1][nf] = mfma16(a1, b, acc[1][nf]);
      }
    }
    __syncthreads();
  }
#pragma unroll
  for (int mf = 0; mf < 2; ++mf)
#pragma unroll
    for (int nf = 0; nf < 8; ++nf)
#pragma unroll
      for (int r = 0; r < 4; ++r) {
        int row = m0 + w * 32 + mf * 16 + q * 4 + r;
        int col = n0 + nf * 16 + ln;
        out[row * 3072 + col] = acc[mf][nf][r] + bias[col];
      }
}

// ---- GEMM: Wc = W_ih @ W_fc -> packed Wcomb slabs 0..2
__global__ __launch_bounds__(256) void k_gemm_wc(
    const float* __restrict__ A, const short* __restrict__ Bp,
    short* __restrict__ wcomb) {
  __shared__ short As[128 * 72];
  __shared__ short Bs[8 * 128 * 8];
  const int n0 = blockIdx.x * 128, m0 = blockIdx.y * 128;  // n over kh(1024), m over i(3072)
  const int tid = threadIdx.x;
  const int w = tid >> 6, ln = tid & 15, q = (tid >> 4) & 3;
  f32x4 acc[2][8] = {};
  for (int kb = 0; kb < 768; kb += 64) {
#pragma unroll
    for (int rep = 0; rep < 4; ++rep) {
      int id = tid + rep * 256;
      int row = id >> 3, cc = id & 7;
      const float* sa = A + (m0 + row) * OUTD + kb + cc * 8;
      *(s16x8*)&As[row * 72 + cc * 8] = cvt8(*(const float4*)sa, *(const float4*)(sa + 4));
      int kcl = id >> 7, c = id & 127;
      *(uint4*)&Bs[(kcl * 128 + c) * 8] =
          *(const uint4*)(Bp + (size_t)((kb >> 3) + kcl) * (HID * 8) + (n0 + c) * 8);
    }
    __syncthreads();
#pragma unroll
    for (int ks = 0; ks < 2; ++ks) {
      bf16x8 a0 = *(const bf16x8*)&As[(w * 32 + ln) * 72 + ks * 32 + q * 8];
      bf16x8 a1 = *(const bf16x8*)&As[(w * 32 + 16 + ln) * 72 + ks * 32 + q * 8];
#pragma unroll
      for (int nf = 0; nf < 8; ++nf) {
        bf16x8 b = *(const bf16x8*)&Bs[((ks * 4 + q) * 128 + nf * 16 + ln) * 8];
        acc[0][nf] = mfma16(a0, b, acc[0][nf]);
        acc[1][nf] = mfma16(a1, b, acc[1][nf]);
      }
    }
    __syncthreads();
  }
#pragma unroll
  for (int mf = 0; mf < 2; ++mf)
#pragma unroll
    for (int nf = 0; nf < 8; ++nf)
#pragma unroll
      for (int r = 0; r < 4; ++r) {
        int i = m0 + w * 32 + mf * 16 + q * 4 + r;
        int kh = n0 + nf * 16 + ln;
        int g = i >> 10, j = i & 1023;
        wcomb[(size_t)(((j >> 3) * 128 + (kh >> 3)) * 48 + g * 8 + (j & 7)) * 8 + (kh & 7)] =
            f2bf(acc[mf][nf][r]);
      }
}

// ---- final FC: out = Hs @ W_fc.T + b_fc   (A bf16 [65536][1024], Bp packed)
__global__ __launch_bounds__(256) void k_gemm_fc(
    const short* __restrict__ A, const short* __restrict__ Bp,
    const float* __restrict__ bias, float* __restrict__ out) {
  __shared__ short As[128 * 72];
  __shared__ short Bs[8 * 128 * 8];
  const int n0 = blockIdx.x * 128, m0 = blockIdx.y * 128;
  const int tid = threadIdx.x;
  const int w = tid >> 6, ln = tid & 15, q = (tid >> 4) & 3;
  f32x4 acc[2][8] = {};
  for (int kb = 0; kb < 1024; kb += 64) {
#pragma unroll
    for (int rep = 0; rep < 4; ++rep) {
      int id = tid + rep * 256;
      int row = id >> 3, cc = id & 7;
      *(uint4*)&As[row * 72 + cc * 8] =
          *(const uint4*)(A + (size_t)(m0 + row) * HID + kb + cc * 8);
      int kcl = id >> 7, c = id & 127;
      *(uint4*)&Bs[(kcl * 128 + c) * 8] =
          *(const uint4*)(Bp + (size_t)((kb >> 3) + kcl) * (OUTD * 8) + (n0 + c) * 8);
    }
    __syncthreads();
#pragma unroll
    for (int ks = 0; ks < 2; ++ks) {
      bf16x8 a0 = *(const bf16x8*)&As[(w * 32 + ln) * 72 + ks * 32 + q * 8];
      bf16x8 a1 = *(const bf16x8*)&As[(w * 32 + 16 + ln) * 72 + ks * 32 + q * 8];
#pragma unroll
      for (int nf = 0; nf < 8; ++nf) {
        bf16x8 b = *(const bf16x8*)&Bs[((ks * 4 + q) * 128 + nf * 16 + ln) * 8];
        acc[0][nf] = mfma16(a0, b, acc[0][nf]);
        acc[1][nf] = mfma16(a1, b, acc[1][nf]);
      }
    }
    __syncthreads();
  }
#pragma unroll
  for (int mf = 0; mf < 2; ++mf)
#pragma unroll
    for (int nf = 0; nf < 8; ++nf)
#pragma unroll
      for (int r = 0; r < 4; ++r) {
        int row = m0 + w * 32 + mf * 16 + q * 4 + r;
        int col = n0 + nf * 16 + ln;
        out[(size_t)row * OUTD + col] = acc[mf][nf][r] + bias[col];
      }
}

// ---- persistent recurrent kernel: all 256 GRU steps in one launch -------
// PLAIN launch (not cooperative: harness graph-capture rejects coop API).
// Co-residency by construction: grid 256 = CU count, 1 block/CU (130 KB LDS,
// __launch_bounds__(256,1)). Block (jt, mh): jt = 8 hidden units, mh = batch
// half. Wcomb slice lives in LDS all 256 steps; h-state + biases in registers.
__global__ __launch_bounds__(256, 1) void k_persist(
    const short* __restrict__ h0, short* __restrict__ hs,
    const short* __restrict__ wcomb, const float* __restrict__ bcv,
    const float* __restrict__ bhh, const float* __restrict__ gi0,
    const float* __restrict__ hidden, unsigned* __restrict__ cnt) {
  __shared__ short Bp[49152];          // 96 KB: [kc=128][c=48][e=8] for this jt
  __shared__ short As[128 * 136];      // 34 KB A staging (f32 Cb overlay in epilogue)
  const int bid = blockIdx.x;
  const int jt = bid & 127, m0 = (bid >> 7) * 128;
  const int tid = threadIdx.x;
  const int w = tid >> 6, ln = tid & 15, q = (tid >> 4) & 3;

  // one-time persistent B load: 49152 shorts = 12288 uint4
  {
    const uint4* s = (const uint4*)(wcomb + (size_t)jt * 49152);
    uint4* d = (uint4*)Bp;
    for (int r = 0; r < 48; ++r) d[tid + r * 256] = s[tid + r * 256];
  }
  // per-thread persistent gate state: 4 outputs o = tid + rep*256 -> (m=o>>3, jl)
  const int jl = tid & 7, jg = jt * 8 + jl;      // jl identical across reps (256%8==0)
  const float bcr = bcv[jg], bcz = bcv[1024 + jg], bcn = bcv[2048 + jg];
  const float bhr = bhh[jg], bhz = bhh[1024 + jg], bhn = bhh[2048 + jg];
  float hv[4];
#pragma unroll
  for (int rep = 0; rep < 4; ++rep) {
    int m = (tid + rep * 256) >> 3;
    hv[rep] = hidden[(m0 + m) * HID + jg];
  }

  for (int k = 0; k < 256; ++k) {
    const short* Ab = ((k == 0) ? h0 : hs + (size_t)(k - 1) * 262144) + (size_t)m0 * HID;
    f32x4 acc[2][3] = {};
    uint4 pre[8];
#pragma unroll
    for (int r = 0; r < 8; ++r) {
      int id = tid + r * 256, row = id >> 4, cc = id & 15;
      pre[r] = *(const uint4*)(Ab + row * HID + cc * 8);
    }
    for (int kb = 0; kb < 8; ++kb) {
#pragma unroll
      for (int r = 0; r < 8; ++r) {
        int id = tid + r * 256, row = id >> 4, cc = id & 15;
        *(uint4*)&As[row * 136 + cc * 8] = pre[r];
      }
      __syncthreads();                 // also covers first-use of Bp at k==0,kb==0
      if (kb < 7) {
#pragma unroll
        for (int r = 0; r < 8; ++r) {  // prefetch next chunk under the MFMAs
          int id = tid + r * 256, row = id >> 4, cc = id & 15;
          pre[r] = *(const uint4*)(Ab + row * HID + (kb + 1) * 128 + cc * 8);
        }
      }
#pragma unroll
      for (int ks = 0; ks < 4; ++ks) {
        bf16x8 a0 = *(const bf16x8*)&As[(w * 32 + ln) * 136 + ks * 32 + q * 8];
        bf16x8 a1 = *(const bf16x8*)&As[(w * 32 + 16 + ln) * 136 + ks * 32 + q * 8];
#pragma unroll
        for (int nf = 0; nf < 3; ++nf) {
          bf16x8 b = *(const bf16x8*)&Bp[((kb * 16 + ks * 4 + q) * 48 + nf * 16 + ln) * 8];
          acc[0][nf] = mfma16(a0, b, acc[0][nf]);
          acc[1][nf] = mfma16(a1, b, acc[1][nf]);
        }
      }
      __syncthreads();
    }
    // epilogue: stage C through LDS overlay, fused gates, h in registers
    float* Cb = (float*)As;            // [128][49] f32
#pragma unroll
    for (int mf = 0; mf < 2; ++mf)
#pragma unroll
      for (int nf = 0; nf < 3; ++nf)
#pragma unroll
        for (int r = 0; r < 4; ++r)
          Cb[(w * 32 + mf * 16 + q * 4 + r) * 49 + nf * 16 + ln] = acc[mf][nf][r];
    __syncthreads();
    short* hso = hs + (size_t)k * 262144;
#pragma unroll
    for (int rep = 0; rep < 4; ++rep) {
      int o = tid + rep * 256, m = o >> 3;
      int bg = m0 + m;
      const float* cr = &Cb[m * 49 + jl];
      float ir, iz, inn;
      if (k == 0) {                    // step 0: gi from src[0] path (already biased)
        const float* g = gi0 + bg * 3072 + jg;
        ir = g[0]; iz = g[1024]; inn = g[2048];
      } else {
        ir = cr[0] + bcr; iz = cr[8] + bcz; inn = cr[16] + bcn;
      }
      float hr = cr[24] + bhr, hz = cr[32] + bhz, hn = cr[40] + bhn;
      float rr = 1.f / (1.f + __expf(-(ir + hr)));
      float zz = 1.f / (1.f + __expf(-(iz + hz)));
      float nn = tanhf(inn + rr * hn);
      float h = (1.f - zz) * nn + zz * hv[rep];
      hv[rep] = h;
      hso[bg * HID + jg] = f2bf(h);
    }
    // grid barrier: __syncthreads drains this block's hs stores to L2;
    // tid0's RELEASE fetch_add publishes (L2 writeback to L3); relaxed spin;
    // final ACQUIRE load invalidates L2 so next step's A reads see other
    // XCDs' fresh hs[k]. (Per-block persistent data is in LDS/regs, so the
    // invalidate costs no reuse.)
    if (k < 255) {
      __syncthreads();
      if (tid == 0) {
        __hip_atomic_fetch_add(cnt, 1u, __ATOMIC_RELEASE, __HIP_MEMORY_SCOPE_AGENT);
        unsigned tgt = (unsigned)(k + 1) * 256u;
        while (__hip_atomic_load(cnt, __ATOMIC_RELAXED, __HIP_MEMORY_SCOPE_AGENT) < tgt)
          __builtin_amdgcn_s_sleep(2);
        (void)__hip_atomic_load(cnt, __ATOMIC_ACQUIRE, __HIP_MEMORY_SCOPE_AGENT);
      }
      __syncthreads();
    }
  }
}

// ---- host ---------------------------------------------------------------

extern "C" void kernel_launch(void* const* d_in, const int* in_sizes, int n_in,
                              void* d_out, int out_size, void* d_ws, size_t ws_size,
                              hipStream_t stream) {
  const float* src    = (const float*)d_in[0];
  const float* hidden = (const float*)d_in[2];
  const float* wih    = (const float*)d_in[3];
  const float* whh    = (const float*)d_in[4];
  const float* bih    = (const float*)d_in[5];
  const float* bhh    = (const float*)d_in[6];
  const float* wfc    = (const float*)d_in[7];
  const float* bfc    = (const float*)d_in[8];
  float* out = (float*)d_out;

  char* p = (char*)d_ws;
  auto alloc = [&](size_t bytes) { char* r = p; p += (bytes + 255) & ~(size_t)255; return r; };
  short* wcomb = (short*)alloc(6291456ull * 2);   // [128][128][48][8] bf16
  short* wfcp  = (short*)alloc(786432ull * 2);    // FC B packed
  short* wfc2p = (short*)alloc(786432ull * 2);    // Wc B packed
  float* gi0   = (float*)alloc(786432ull * 4);    // [256][3072]
  float* bcv   = (float*)alloc(3072ull * 4);
  short* h0    = (short*)alloc(262144ull * 2);
  unsigned* cnt = (unsigned*)alloc(256);
  short* hs    = (short*)alloc(67108864ull * 2);  // [256][256][1024] bf16
  size_t need = (size_t)(p - (char*)d_ws);
  if (ws_size < need) {  // distinctive failure signature
    k_flag<<<(out_size + 255) / 256, 256, 0, stream>>>(out, out_size);
    return;
  }

  k_pack_whh <<<1536, 256, 0, stream>>>(whh, wcomb);
  k_pack_wfc <<<384,  256, 0, stream>>>(wfc, wfcp);
  k_pack_wfc2<<<384,  256, 0, stream>>>(wfc, wfc2p);
  k_h0       <<<1024, 256, 0, stream>>>(hidden, h0, cnt);
  k_bc       <<<768,  256, 0, stream>>>(wih, bih, bfc, bcv);
  k_gemm_wc  <<<dim3(8, 24), 256, 0, stream>>>(wih, wfc2p, wcomb);
  k_gemm_bt  <<<dim3(24, 2), 256, 0, stream>>>(src, wih, bih, gi0);

  // all 256 recurrent steps in one persistent launch (grid == CU count)
  k_persist<<<dim3(256), 256, 0, stream>>>(h0, hs, wcomb, bcv, bhh, gi0, hidden, cnt);

  k_gemm_fc<<<dim3(6, 512), 256, 0, stream>>>(hs, wfcp, bfc, out);
}

// Round 4
// 3793.618 us; speedup vs baseline: 2.5016x; 2.5016x over previous
//
#include <hip/hip_runtime.h>

#define HID 1024
#define OUTD 768

typedef __attribute__((ext_vector_type(8))) __bf16 bf16x8;
typedef __attribute__((ext_vector_type(8))) short s16x8;
typedef __attribute__((ext_vector_type(4))) float f32x4;

__device__ __forceinline__ short f2bf(float f) {
  unsigned u = __builtin_bit_cast(unsigned, f);
  u = (u + 0x7fffu + ((u >> 16) & 1u)) >> 16;   // RNE
  return (short)u;
}

__device__ __forceinline__ s16x8 cvt8(float4 a, float4 b) {
  s16x8 r;
  r[0] = f2bf(a.x); r[1] = f2bf(a.y); r[2] = f2bf(a.z); r[3] = f2bf(a.w);
  r[4] = f2bf(b.x); r[5] = f2bf(b.y); r[6] = f2bf(b.z); r[7] = f2bf(b.w);
  return r;
}

__device__ __forceinline__ f32x4 mfma16(bf16x8 a, bf16x8 b, f32x4 c) {
  return __builtin_amdgcn_mfma_f32_16x16x32_bf16(a, b, c, 0, 0, 0);
}

// ---- pack kernels -------------------------------------------------------

// W_hh [3072][1024] -> Wcomb packed [t=128][kc=128][c=48][8], slabs c in [24,48)
__global__ void k_pack_whh(const float* __restrict__ whh, short* __restrict__ wcomb) {
  int id = blockIdx.x * 256 + threadIdx.x;        // 3072*128
  int i = id >> 7, kc = id & 127;
  const float* s = whh + i * HID + kc * 8;
  int g = i >> 10, j = i & 1023;
  int dst = (((j >> 3) * 128 + kc) * 48 + 24 + g * 8 + (j & 7)) * 8;
  *(s16x8*)(wcomb + dst) = cvt8(*(const float4*)s, *(const float4*)(s + 4));
}

// W_fc [768][1024] -> FC-B packed [kc=128][n=768][8]  (k-dim = HID)
__global__ void k_pack_wfc(const float* __restrict__ wfc, short* __restrict__ wfcp) {
  int id = blockIdx.x * 256 + threadIdx.x;        // 768*128
  int r = id >> 7, c8 = id & 127;
  const float* s = wfc + r * HID + c8 * 8;
  *(s16x8*)(wfcp + (c8 * OUTD + r) * 8) = cvt8(*(const float4*)s, *(const float4*)(s + 4));
}

// W_fc [768][1024] -> Wc-B packed [kc=96][n=1024][8]  (k-dim = OUTD)
__global__ void k_pack_wfc2(const float* __restrict__ wfc, short* __restrict__ wfc2p) {
  int id = blockIdx.x * 256 + threadIdx.x;        // 96*1024
  int r8 = id >> 10, c = id & 1023;
  s16x8 v;
#pragma unroll
  for (int p = 0; p < 8; ++p) v[p] = f2bf(wfc[(r8 * 8 + p) * HID + c]);
  *(s16x8*)(wfc2p + (r8 * HID + c) * 8) = v;
}

__global__ void k_h0(const float* __restrict__ hidden, short* __restrict__ h0,
                     unsigned* __restrict__ cnt) {
  int id = blockIdx.x * 256 + threadIdx.x;        // 262144
  h0[id] = f2bf(hidden[id]);
  if (id == 0) *cnt = 0u;
}

// bc[i] = b_ih[i] + sum_o W_ih[i][o] * b_fc[o]
__global__ void k_bc(const float* __restrict__ wih, const float* __restrict__ bih,
                     const float* __restrict__ bfc, float* __restrict__ bc) {
  int w = threadIdx.x >> 6, lane = threadIdx.x & 63;
  int i = blockIdx.x * 4 + w;                     // grid 768
  float s = 0.f;
#pragma unroll
  for (int it = 0; it < 12; ++it) {
    int o = lane + it * 64;
    s += wih[i * OUTD + o] * bfc[o];
  }
  for (int off = 32; off; off >>= 1) s += __shfl_down(s, off);
  if (lane == 0) bc[i] = bih[i] + s;
}

__global__ void k_flag(float* out, int n) {
  int i = blockIdx.x * 256 + threadIdx.x;
  if (i < n) out[i] = 12345.0f;
}

// ---- GEMM: gi0 = src0 @ W_ih.T + b_ih   (A f32 [256][768], Bt f32 [3072][768])
__global__ __launch_bounds__(256) void k_gemm_bt(
    const float* __restrict__ A, const float* __restrict__ Bt,
    const float* __restrict__ bias, float* __restrict__ out) {
  __shared__ short As[128 * 72];
  __shared__ short Bs[128 * 72];
  const int n0 = blockIdx.x * 128, m0 = blockIdx.y * 128;
  const int tid = threadIdx.x;
  const int w = tid >> 6, ln = tid & 15, q = (tid >> 4) & 3;
  f32x4 acc[2][8] = {};
  for (int kb = 0; kb < 768; kb += 64) {
#pragma unroll
    for (int rep = 0; rep < 4; ++rep) {
      int id = tid + rep * 256;
      int row = id >> 3, cc = id & 7;
      const float* sa = A + (m0 + row) * OUTD + kb + cc * 8;
      *(s16x8*)&As[row * 72 + cc * 8] = cvt8(*(const float4*)sa, *(const float4*)(sa + 4));
      const float* sb = Bt + (n0 + row) * OUTD + kb + cc * 8;
      *(s16x8*)&Bs[row * 72 + cc * 8] = cvt8(*(const float4*)sb, *(const float4*)(sb + 4));
    }
    __syncthreads();
#pragma unroll
    for (int ks = 0; ks < 2; ++ks) {
      bf16x8 a0 = *(const bf16x8*)&As[(w * 32 + ln) * 72 + ks * 32 + q * 8];
      bf16x8 a1 = *(const bf16x8*)&As[(w * 32 + 16 + ln) * 72 + ks * 32 + q * 8];
#pragma unroll
      for (int nf = 0; nf < 8; ++nf) {
        bf16x8 b = *(const bf16x8*)&Bs[(nf * 16 + ln) * 72 + ks * 32 + q * 8];
        acc[0][nf] = mfma16(a0, b, acc[0][nf]);
        acc[1][nf] = mfma16(a1, b, acc[1][nf]);
      }
    }
    __syncthreads();
  }
#pragma unroll
  for (int mf = 0; mf < 2; ++mf)
#pragma unroll
    for (int nf = 0; nf < 8; ++nf)
#pragma unroll
      for (int r = 0; r < 4; ++r) {
        int row = m0 + w * 32 + mf * 16 + q * 4 + r;
        int col = n0 + nf * 16 + ln;
        out[row * 3072 + col] = acc[mf][nf][r] + bias[col];
      }
}

// ---- GEMM: Wc = W_ih @ W_fc -> packed Wcomb slabs 0..2
__global__ __launch_bounds__(256) void k_gemm_wc(
    const float* __restrict__ A, const short* __restrict__ Bp,
    short* __restrict__ wcomb) {
  __shared__ short As[128 * 72];
  __shared__ short Bs[8 * 128 * 8];
  const int n0 = blockIdx.x * 128, m0 = blockIdx.y * 128;  // n over kh(1024), m over i(3072)
  const int tid = threadIdx.x;
  const int w = tid >> 6, ln = tid & 15, q = (tid >> 4) & 3;
  f32x4 acc[2][8] = {};
  for (int kb = 0; kb < 768; kb += 64) {
#pragma unroll
    for (int rep = 0; rep < 4; ++rep) {
      int id = tid + rep * 256;
      int row = id >> 3, cc = id & 7;
      const float* sa = A + (m0 + row) * OUTD + kb + cc * 8;
      *(s16x8*)&As[row * 72 + cc * 8] = cvt8(*(const float4*)sa, *(const float4*)(sa + 4));
      int kcl = id >> 7, c = id & 127;
      *(uint4*)&Bs[(kcl * 128 + c) * 8] =
          *(const uint4*)(Bp + (size_t)((kb >> 3) + kcl) * (HID * 8) + (n0 + c) * 8);
    }
    __syncthreads();
#pragma unroll
    for (int ks = 0; ks < 2; ++ks) {
      bf16x8 a0 = *(const bf16x8*)&As[(w * 32 + ln) * 72 + ks * 32 + q * 8];
      bf16x8 a1 = *(const bf16x8*)&As[(w * 32 + 16 + ln) * 72 + ks * 32 + q * 8];
#pragma unroll
      for (int nf = 0; nf < 8; ++nf) {
        bf16x8 b = *(const bf16x8*)&Bs[((ks * 4 + q) * 128 + nf * 16 + ln) * 8];
        acc[0][nf] = mfma16(a0, b, acc[0][nf]);
        acc[1][nf] = mfma16(a1, b, acc[1][nf]);
      }
    }
    __syncthreads();
  }
#pragma unroll
  for (int mf = 0; mf < 2; ++mf)
#pragma unroll
    for (int nf = 0; nf < 8; ++nf)
#pragma unroll
      for (int r = 0; r < 4; ++r) {
        int i = m0 + w * 32 + mf * 16 + q * 4 + r;
        int kh = n0 + nf * 16 + ln;
        int g = i >> 10, j = i & 1023;
        wcomb[(size_t)(((j >> 3) * 128 + (kh >> 3)) * 48 + g * 8 + (j & 7)) * 8 + (kh & 7)] =
            f2bf(acc[mf][nf][r]);
      }
}

// ---- final FC: out = Hs @ W_fc.T + b_fc   (A bf16 [65536][1024], Bp packed)
__global__ __launch_bounds__(256) void k_gemm_fc(
    const short* __restrict__ A, const short* __restrict__ Bp,
    const float* __restrict__ bias, float* __restrict__ out) {
  __shared__ short As[128 * 72];
  __shared__ short Bs[8 * 128 * 8];
  const int n0 = blockIdx.x * 128, m0 = blockIdx.y * 128;
  const int tid = threadIdx.x;
  const int w = tid >> 6, ln = tid & 15, q = (tid >> 4) & 3;
  f32x4 acc[2][8] = {};
  for (int kb = 0; kb < 1024; kb += 64) {
#pragma unroll
    for (int rep = 0; rep < 4; ++rep) {
      int id = tid + rep * 256;
      int row = id >> 3, cc = id & 7;
      *(uint4*)&As[row * 72 + cc * 8] =
          *(const uint4*)(A + (size_t)(m0 + row) * HID + kb + cc * 8);
      int kcl = id >> 7, c = id & 127;
      *(uint4*)&Bs[(kcl * 128 + c) * 8] =
          *(const uint4*)(Bp + (size_t)((kb >> 3) + kcl) * (OUTD * 8) + (n0 + c) * 8);
    }
    __syncthreads();
#pragma unroll
    for (int ks = 0; ks < 2; ++ks) {
      bf16x8 a0 = *(const bf16x8*)&As[(w * 32 + ln) * 72 + ks * 32 + q * 8];
      bf16x8 a1 = *(const bf16x8*)&As[(w * 32 + 16 + ln) * 72 + ks * 32 + q * 8];
#pragma unroll
      for (int nf = 0; nf < 8; ++nf) {
        bf16x8 b = *(const bf16x8*)&Bs[((ks * 4 + q) * 128 + nf * 16 + ln) * 8];
        acc[0][nf] = mfma16(a0, b, acc[0][nf]);
        acc[1][nf] = mfma16(a1, b, acc[1][nf]);
      }
    }
    __syncthreads();
  }
#pragma unroll
  for (int mf = 0; mf < 2; ++mf)
#pragma unroll
    for (int nf = 0; nf < 8; ++nf)
#pragma unroll
      for (int r = 0; r < 4; ++r) {
        int row = m0 + w * 32 + mf * 16 + q * 4 + r;
        int col = n0 + nf * 16 + ln;
        out[(size_t)row * OUTD + col] = acc[mf][nf][r] + bias[col];
      }
}

// ---- persistent recurrent kernel: all 256 GRU steps in one launch -------
// Plain launch; co-residency by construction (grid 256 = CU count, 1 block/CU
// via 121 KB LDS). NO cache-maintenance ops in the loop: h published via
// relaxed agent-scope atomic stores (sc1 write-through to L3, L2 stays clean),
// barrier = vmcnt-drain (syncthreads) + relaxed fetch_add + relaxed spin.
// Readers' A loads are first-touch lines each step (write-once/read-once), so
// plain cached loads are coherent; dispatch-start acquire clears prior-replay
// stale lines. A fragments load straight from global (no LDS staging: each
// wave consumes only its own 32 A rows).
__global__ __launch_bounds__(256, 1) void k_persist(
    const short* __restrict__ h0, short* __restrict__ hs,
    const short* __restrict__ wcomb, const float* __restrict__ bcv,
    const float* __restrict__ bhh, const float* __restrict__ gi0,
    const float* __restrict__ hidden, unsigned* __restrict__ cnt) {
  __shared__ short Bp[49152];          // 96 KB: [kc=128][c=48][e=8] for this jt
  __shared__ float Cb[128 * 49];       // 25 KB epilogue exchange
  const int bid = blockIdx.x;
  const int jt = bid & 127, m0 = (bid >> 7) * 128;
  const int tid = threadIdx.x;
  const int w = tid >> 6, ln = tid & 15, q = (tid >> 4) & 3;

  // one-time persistent B load: 49152 shorts = 12288 uint4
  {
    const uint4* s = (const uint4*)(wcomb + (size_t)jt * 49152);
    uint4* d = (uint4*)Bp;
    for (int r = 0; r < 48; ++r) d[tid + r * 256] = s[tid + r * 256];
  }

  // epilogue mapping: thread owns (row mrow, 4 cols jgb..jgb+3) -> one 8B store
  const int mrow = tid >> 1;                    // 0..127
  const int half = tid & 1;
  const int jgb = jt * 8 + half * 4;            // global hidden-col base
  const float4 bcr4 = *(const float4*)(bcv + jgb);
  const float4 bcz4 = *(const float4*)(bcv + 1024 + jgb);
  const float4 bcn4 = *(const float4*)(bcv + 2048 + jgb);
  const float4 bhr4 = *(const float4*)(bhh + jgb);
  const float4 bhz4 = *(const float4*)(bhh + 1024 + jgb);
  const float4 bhn4 = *(const float4*)(bhh + 2048 + jgb);
  float4 hv = *(const float4*)(hidden + (size_t)(m0 + mrow) * HID + jgb);
  __syncthreads();                              // Bp ready

  for (int k = 0; k < 256; ++k) {
    const short* Ab = ((k == 0) ? h0 : hs + (size_t)(k - 1) * 262144) + (size_t)m0 * HID;
    const short* ar0 = Ab + (w * 32 + ln) * HID + q * 8;   // wave's a0 row
    const short* ar1 = ar0 + 16 * HID;                     // wave's a1 row
    f32x4 acc[2][3] = {};
#pragma unroll
    for (int kb = 0; kb < 8; ++kb) {
#pragma unroll
      for (int ks = 0; ks < 4; ++ks) {
        bf16x8 a0 = *(const bf16x8*)(ar0 + kb * 128 + ks * 32);
        bf16x8 a1 = *(const bf16x8*)(ar1 + kb * 128 + ks * 32);
#pragma unroll
        for (int nf = 0; nf < 3; ++nf) {
          bf16x8 b = *(const bf16x8*)&Bp[((kb * 16 + ks * 4 + q) * 48 + nf * 16 + ln) * 8];
          acc[0][nf] = mfma16(a0, b, acc[0][nf]);
          acc[1][nf] = mfma16(a1, b, acc[1][nf]);
        }
      }
    }
    // stage C through LDS to re-map (MFMA frag layout) -> (row, col) threads
#pragma unroll
    for (int mf = 0; mf < 2; ++mf)
#pragma unroll
      for (int nf = 0; nf < 3; ++nf)
#pragma unroll
        for (int r = 0; r < 4; ++r)
          Cb[(w * 32 + mf * 16 + q * 4 + r) * 49 + nf * 16 + ln] = acc[mf][nf][r];
    __syncthreads();
    // fused gates: 4 outputs per thread (row mrow, cols jgb+0..3)
    const float* cr = &Cb[mrow * 49 + half * 4];
    const float* gbase = gi0 + (size_t)(m0 + mrow) * 3072 + jgb;
    float hn4[4];
#pragma unroll
    for (int rep = 0; rep < 4; ++rep) {
      float c0 = cr[rep], c1 = cr[rep + 8], c2 = cr[rep + 16];
      float c3 = cr[rep + 24], c4 = cr[rep + 32], c5 = cr[rep + 40];
      float ir, iz, inn;
      if (k == 0) {                    // step 0: gi from src[0] path (already biased)
        ir = gbase[rep]; iz = gbase[1024 + rep]; inn = gbase[2048 + rep];
      } else {
        ir = c0 + (&bcr4.x)[rep]; iz = c1 + (&bcz4.x)[rep]; inn = c2 + (&bcn4.x)[rep];
      }
      float hr = c3 + (&bhr4.x)[rep], hz = c4 + (&bhz4.x)[rep], hnn = c5 + (&bhn4.x)[rep];
      float rr = 1.f / (1.f + __expf(-(ir + hr)));
      float zz = 1.f / (1.f + __expf(-(iz + hz)));
      float nn = tanhf(inn + rr * hnn);
      hn4[rep] = (1.f - zz) * nn + zz * (&hv.x)[rep];
    }
    hv.x = hn4[0]; hv.y = hn4[1]; hv.z = hn4[2]; hv.w = hn4[3];
    unsigned long long pk =
        (unsigned long long)(unsigned short)f2bf(hn4[0]) |
        ((unsigned long long)(unsigned short)f2bf(hn4[1]) << 16) |
        ((unsigned long long)(unsigned short)f2bf(hn4[2]) << 32) |
        ((unsigned long long)(unsigned short)f2bf(hn4[3]) << 48);
    __hip_atomic_store(
        (unsigned long long*)(hs + (size_t)k * 262144 + (size_t)(m0 + mrow) * HID + jgb),
        pk, __ATOMIC_RELAXED, __HIP_MEMORY_SCOPE_AGENT);   // sc1 write-through
    if (k < 255) {
      __syncthreads();   // vmcnt(0) drain per wave: all sc1 stores are in L3
      if (tid == 0) {
        __hip_atomic_fetch_add(cnt, 1u, __ATOMIC_RELAXED, __HIP_MEMORY_SCOPE_AGENT);
        unsigned tgt = (unsigned)(k + 1) * 256u;
        while (__hip_atomic_load(cnt, __ATOMIC_RELAXED, __HIP_MEMORY_SCOPE_AGENT) < tgt)
          __builtin_amdgcn_s_sleep(1);
      }
      asm volatile("" ::: "memory");   // keep next step's loads below the spin
      __syncthreads();
    }
  }
}

// ---- host ---------------------------------------------------------------

extern "C" void kernel_launch(void* const* d_in, const int* in_sizes, int n_in,
                              void* d_out, int out_size, void* d_ws, size_t ws_size,
                              hipStream_t stream) {
  const float* src    = (const float*)d_in[0];
  const float* hidden = (const float*)d_in[2];
  const float* wih    = (const float*)d_in[3];
  const float* whh    = (const float*)d_in[4];
  const float* bih    = (const float*)d_in[5];
  const float* bhh    = (const float*)d_in[6];
  const float* wfc    = (const float*)d_in[7];
  const float* bfc    = (const float*)d_in[8];
  float* out = (float*)d_out;

  char* p = (char*)d_ws;
  auto alloc = [&](size_t bytes) { char* r = p; p += (bytes + 255) & ~(size_t)255; return r; };
  short* wcomb = (short*)alloc(6291456ull * 2);   // [128][128][48][8] bf16
  short* wfcp  = (short*)alloc(786432ull * 2);    // FC B packed
  short* wfc2p = (short*)alloc(786432ull * 2);    // Wc B packed
  float* gi0   = (float*)alloc(786432ull * 4);    // [256][3072]
  float* bcv   = (float*)alloc(3072ull * 4);
  short* h0    = (short*)alloc(262144ull * 2);
  unsigned* cnt = (unsigned*)alloc(256);
  short* hs    = (short*)alloc(67108864ull * 2);  // [256][256][1024] bf16
  size_t need = (size_t)(p - (char*)d_ws);
  if (ws_size < need) {  // distinctive failure signature
    k_flag<<<(out_size + 255) / 256, 256, 0, stream>>>(out, out_size);
    return;
  }

  k_pack_whh <<<1536, 256, 0, stream>>>(whh, wcomb);
  k_pack_wfc <<<384,  256, 0, stream>>>(wfc, wfcp);
  k_pack_wfc2<<<384,  256, 0, stream>>>(wfc, wfc2p);
  k_h0       <<<1024, 256, 0, stream>>>(hidden, h0, cnt);
  k_bc       <<<768,  256, 0, stream>>>(wih, bih, bfc, bcv);
  k_gemm_wc  <<<dim3(8, 24), 256, 0, stream>>>(wih, wfc2p, wcomb);
  k_gemm_bt  <<<dim3(24, 2), 256, 0, stream>>>(src, wih, bih, gi0);

  // all 256 recurrent steps in one persistent launch (grid == CU count)
  k_persist<<<dim3(256), 256, 0, stream>>>(h0, hs, wcomb, bcv, bhh, gi0, hidden, cnt);

  k_gemm_fc<<<dim3(6, 512), 256, 0, stream>>>(hs, wfcp, bfc, out);
}